// Round 12
// baseline (75.728 us; speedup 1.0000x reference)
//
#include <hip/hip_runtime.h>
#include <cstdint>
#include <cstddef>

#define NB 128      // N
#define KPP 32      // Kp
#define VV 2048     // V
#define SS 200      // S (tm1)
#define WID 32      // width == K
#define NEXT_BASE (KPP*VV)     // 65536
#define KBLK 16                // blocks per n (each block = 4 waves = 2 rows x 2 halves)
#define CAPW 128               // per-wave survivor cap
#define NWAVE (KPP*2)          // 64 waves per n
#define FCAP 1024              // merge filtered-list cap (overflow -> exact cold path)

// output layout (flat f32, concat in return order)
#define SZ_YNEXT ((size_t)(SS+1)*NB*WID)               // 823296
#define NK       ((size_t)NB*WID)                      // 4096
#define O_LAST   (SZ_YNEXT)
#define O_LENS   (SZ_YNEXT + NK)
#define O_NB     (SZ_YNEXT + 2*NK)
#define O_B      (SZ_YNEXT + 3*NK)
#define O_PREF   (SZ_YNEXT + 4*NK)                     // size NB*WID*WID
#define O_SRC    (SZ_YNEXT + 4*NK + (size_t)NB*WID*WID)
#define O_NOEXT  (SZ_YNEXT + 5*NK + (size_t)NB*WID*WID)

__device__ __forceinline__ unsigned fkey(float f) {
    unsigned u = __float_as_uint(f);
    return (u & 0x80000000u) ? ~u : (u | 0x80000000u);
}
__device__ __forceinline__ float funkey(unsigned k) {
    unsigned u = (k & 0x80000000u) ? (k & 0x7FFFFFFFu) : ~k;
    return __uint_as_float(u);
}

// ---------------- kernel A: one wave per HALF k-row; no sort, no survivor LDS ----------------
__global__ __launch_bounds__(256) void slice_topk_kernel(
    const float* __restrict__ ext,     // [N][Kp][V]
    const float* __restrict__ nbp_g,   // [N][Kp]
    const float* __restrict__ bp_g,    // [N][Kp]
    const int*   __restrict__ yprev,   // [S][N][Kp]
    const int*   __restrict__ ylast,   // [N][Kp]
    const int*   __restrict__ ylens,   // [N][Kp]
    const int*   __restrict__ pip,     // [N][Kp][Kp]
    uint2* __restrict__ wsS, int* __restrict__ wsC, unsigned* __restrict__ wsT,
    float* __restrict__ wsAb)
{
    const int blk  = blockIdx.x;
    const int n    = blk >> 4;          // KBLK = 16
    const int kb   = blk & 15;
    const int tid  = threadIdx.x;
    const int w    = tid >> 6;          // 4 waves
    const int lane = tid & 63;
    const int k    = kb*2 + (w >> 1);
    const int half = w & 1;
    const int g    = ((n*KPP + k) << 1) + half;   // this wave's list id

    __shared__ unsigned s_hm[4][VV/32];     // wave-private hm (full row), 1 KB

    s_hm[w][lane] = 0u;                 // VV/32 == 64 == lane count (wave-private)

    // per-row params (wave-uniform addresses -> broadcast loads)
    const int   tlen = ylens[n*KPP + k];
    int last = ylast[n*KPP + k]; last = min(max(last, 0), VV-1);
    const float nbp = nbp_g[n*KPP + k];
    const float bp  = bp_g[n*KPP + k];

    // issue the 4 float4 loads early (16 floats/lane, registers only)
    const float4* g4 = (const float4*)(ext + ((size_t)n*KPP + k)*VV + half*1024);
    float4 f[4];
    #pragma unroll
    for (int j = 0; j < 4; ++j) f[j] = g4[lane + 64*j];

    // has-match bits + absorb terms (same-wave LDS ordering; no barrier needed)
    if (lane < KPP) {
        int j = lane;
        int tcl = min(max(tlen, 0), SS-1);
        int tm  = yprev[((size_t)tcl*NB + n)*KPP + j];
        tm = min(max(tm, 0), VV-1);
        bool ex = (tlen + 1 == ylens[n*KPP + j]) && (pip[((size_t)n*KPP + k)*KPP + j] != 0);
        if (ex) atomicOr(&s_hm[w][tm >> 5], 1u << (tm & 31));
        if (half == 0) {
            float ev = ex ? ext[((size_t)n*KPP + k)*VV + tm] : 0.0f;
            float bb = (tm == last) ? 0.0f : nbp;
            wsAb[((size_t)n*KPP + k)*KPP + j] = ex ? (bb + bp)*ev : 0.0f;
        }
    }

    // 16 keys in registers; v_local = 4*lane + 256*j + e in [0,1024)
    unsigned key[16];
    #pragma unroll
    for (int j = 0; j < 4; ++j) {
        const float fe[4] = {f[j].x, f[j].y, f[j].z, f[j].w};
        #pragma unroll
        for (int e = 0; e < 4; ++e) {
            int vl = 4*lane + 256*j + e;
            int v  = (half << 10) + vl;
            float base = (v == last) ? 0.0f : nbp;
            float val  = (base + bp) * fe[e];
            if ((s_hm[w][v >> 5] >> (v & 31)) & 1u) val = -INFINITY;
            key[j*4 + e] = fkey(val);
        }
    }

    // lane max (top 16 bits suffice for the threshold)
    unsigned m = key[0];
    #pragma unroll
    for (int i = 1; i < 16; ++i) m = max(m, key[i]);
    const unsigned m16 = m >> 16;

    // tau16 = EXACT 32nd-largest of the 64 (lane-max >> 16) values: 16 ballot steps
    unsigned tau16 = 0;
    {
        int need = 32;
        #pragma unroll
        for (int b = 15; b >= 0; --b) {
            unsigned pb1 = (tau16 >> b) | 1u;
            unsigned long long msk = __ballot((m16 >> b) == pb1);
            int cnt = __popcll(msk);
            if (cnt >= need) tau16 |= (1u << b);
            else             need -= cnt;
        }
    }
    // guarantee: >=32 lanes have (m>>16) >= tau16  =>  >=32 keys with (key>>16) >= tau16

    // gather survivors DIRECTLY to global (ballot prefix; unsorted)
    const unsigned long long lmask = (1ull << lane) - 1ull;
    uint2* myws = wsS + (size_t)g*CAPW;
    int off2 = 0;
    #pragma unroll
    for (int i = 0; i < 16; ++i) {
        bool sel = (key[i] >> 16) >= tau16;
        unsigned long long msk = __ballot(sel);
        if (sel) {
            int slot = off2 + __popcll(msk & lmask);
            if (slot < CAPW)
                myws[slot] = make_uint2(key[i],
                    (unsigned)((k << 11) + (half << 10) + (4*lane + 256*(i >> 2) + (i & 3))));
        }
        off2 += __popcll(msk);
    }
    int total = off2;
    unsigned outT = tau16;

    if (total > CAPW) {
        // exact fallback: key-bit radix, then idx radix among ties (shuffle-only)
        int need = WID;
        unsigned T = 0, istar = 0;
        for (int b = 31; b >= 0; --b) {
            unsigned pb1 = (T >> b) | 1u;
            int c1 = 0;
            #pragma unroll
            for (int i = 0; i < 16; ++i) c1 += ((key[i] >> b) == pb1) ? 1 : 0;
            #pragma unroll
            for (int off = 32; off; off >>= 1) c1 += __shfl_xor(c1, off);
            if (c1 >= need) T |= (1u << b);
            else need -= c1;
        }
        for (int b = 9; b >= 0; --b) {          // v_local < 1024 -> 10 bits
            int c0 = 0;
            #pragma unroll
            for (int i = 0; i < 16; ++i) {
                unsigned vv = (unsigned)(4*lane + 256*(i >> 2) + (i & 3));
                if (key[i] == T && (vv >> (b+1)) == (istar >> (b+1)) && !((vv >> b) & 1u)) c0++;
            }
            #pragma unroll
            for (int off = 32; off; off >>= 1) c0 += __shfl_xor(c0, off);
            if (c0 >= need) { } else { need -= c0; istar |= (1u << b); }
        }
        int o2 = 0;
        #pragma unroll
        for (int i = 0; i < 16; ++i) {
            unsigned vv = (unsigned)(4*lane + 256*(i >> 2) + (i & 3));
            bool sel = (key[i] > T || (key[i] == T && vv <= istar));
            unsigned long long msk = __ballot(sel);
            if (sel) {
                int slot = o2 + __popcll(msk & lmask);
                myws[slot] = make_uint2(key[i],
                    (unsigned)((k << 11) + (half << 10) + (int)vv));
            }
            o2 += __popcll(msk);
        }
        total = WID;        // exactly 32 written
        outT  = T >> 16;    // still satisfies: >=32 keys with key>>16 >= outT
    }

    if (lane == 0) { wsC[g] = total; wsT[g] = outT; }
}

// ---------------- kernel B: merge (tau16-filtered) + epilogue + prefix + y_next ----------------
__global__ __launch_bounds__(256) void merge_kernel(
    const float* __restrict__ nonext,
    const float* __restrict__ blank,
    const float* __restrict__ nbp_g,
    const float* __restrict__ bp_g,
    const int*   __restrict__ yprev,
    const int*   __restrict__ ylast,
    const int*   __restrict__ ylens,
    const int*   __restrict__ pip,
    const uint2* __restrict__ wsS, const int* __restrict__ wsC,
    const unsigned* __restrict__ wsT, const float* __restrict__ wsAb,
    float* __restrict__ out)
{
    const int n    = blockIdx.x;
    const int tid  = threadIdx.x;
    const int lane = tid & 63;
    const int wv   = tid >> 6;

    __shared__ int      s_last[KPP];
    __shared__ float    s_bne[KPP], s_nbne[KPP];
    __shared__ float    s_abL[KPP][KPP];
    __shared__ unsigned s_M;
    __shared__ int      s_cnt, s_cnt2;
    __shared__ unsigned s_ff[FCAP];
    __shared__ int      s_fi[FCAP];
    __shared__ int      s_part[2][4];
    __shared__ int      s_selidx[WID];
    __shared__ float    s_selval[WID];
    __shared__ int      s_r_src[WID], s_r_lens[WID], s_r_ext[WID], s_r_noext[WID];

    if (tid == 0) { s_cnt = 0; s_cnt2 = 0; }
    if (tid < KPP) {
        int k = tid;
        int last = ylast[n*KPP + k]; last = min(max(last, 0), VV-1);
        float a = nbp_g[n*KPP + k], b = bp_g[n*KPP + k];
        s_last[k] = last;
        s_bne[k]  = (a + b) * blank[n];
        s_nbne[k] = a * nonext[(size_t)n*VV + last];
    }
    for (int i = tid; i < KPP*KPP; i += 256)
        s_abL[i >> 5][i & 31] = wsAb[(size_t)n*KPP*KPP + i];
    // M = max over 64 waves of tau16 (wave 0 only; independent of the above)
    if (tid < 64) {
        unsigned t = wsT[n*NWAVE + tid];
        #pragma unroll
        for (int off = 32; off; off >>= 1) t = max(t, (unsigned)__shfl_xor((int)t, off));
        if (tid == 0) s_M = t;
    }
    __syncthreads();
    if (tid < KPP) {    // absorb: serial k-order sum (bit-exact; zero terms neutral)
        int j = tid;
        float acc = s_nbne[j];
        #pragma unroll
        for (int k = 0; k < KPP; ++k) acc += s_abL[k][j];
        s_nbne[j] = acc;
    }
    __syncthreads();
    const unsigned M = s_M;

    // filter: wave lists (4 threads per list) + nonext; keep key>>16 >= M
    const int    w2  = tid >> 2;
    const int    cw  = wsC[n*NWAVE + w2];
    const uint2* lw  = wsS + ((size_t)n*NWAVE + w2)*CAPW;
    for (int j = tid & 3; j < cw; j += 4) {
        uint2 e = lw[j];
        if ((e.x >> 16) >= M) {
            int slot = atomicAdd(&s_cnt, 1);
            if (slot < FCAP) { s_ff[slot] = e.x; s_fi[slot] = (int)e.y; }
        }
    }
    const unsigned nkk = (tid < KPP) ? fkey(s_nbne[tid] + s_bne[tid]) : 0u;
    if (tid < KPP && (nkk >> 16) >= M) {
        int slot = atomicAdd(&s_cnt, 1);
        if (slot < FCAP) { s_ff[slot] = nkk; s_fi[slot] = NEXT_BASE + tid; }
    }
    __syncthreads();
    const int fcnt = s_cnt;

    if (fcnt <= FCAP) {
        // hot path: exact rank over the filtered (~60-120) list
        for (int e = tid; e < fcnt; e += 256) {
            unsigned mf = s_ff[e]; int mi = s_fi[e];
            int rank = 0;
            for (int j = 0; j < fcnt; ++j) {
                unsigned f = s_ff[j];
                rank += (f > mf || (f == mf && s_fi[j] < mi)) ? 1 : 0;
            }
            if (rank < WID) { s_selidx[rank] = mi; s_selval[rank] = funkey(mf); }
        }
    } else {
        // cold exact path (adversarial ties): block radix over the global lists
        int pp = 0;
        auto blockSum = [&](int v) -> int {
            #pragma unroll
            for (int off = 32; off; off >>= 1) v += __shfl_xor(v, off);
            if (lane == 0) s_part[pp][wv] = v;
            __syncthreads();
            int tot = s_part[pp][0] + s_part[pp][1] + s_part[pp][2] + s_part[pp][3];
            pp ^= 1;
            return tot;
        };
        unsigned T = 0, istar = 0;
        int need = WID;
        for (int b = 31; b >= 0; --b) {
            unsigned pb1 = (T >> b) | 1u;
            int c1 = 0;
            for (int j = tid & 3; j < cw; j += 4) {
                uint2 e = lw[j];
                if ((e.x >> 16) >= M && (e.x >> b) == pb1) c1++;
            }
            if (tid < KPP && (nkk >> 16) >= M && (nkk >> b) == pb1) c1++;
            int tot = blockSum(c1);
            if (tot >= need) T |= (1u << b);
            else need -= tot;
        }
        for (int b = 16; b >= 0; --b) {   // idx < 2^17
            int c0 = 0;
            for (int j = tid & 3; j < cw; j += 4) {
                uint2 e = lw[j];
                if ((e.x >> 16) >= M && e.x == T &&
                    (e.y >> (b+1)) == (istar >> (b+1)) && !((e.y >> b) & 1u)) c0++;
            }
            if (tid < KPP && (nkk >> 16) >= M && nkk == T) {
                unsigned idx = (unsigned)(NEXT_BASE + tid);
                if ((idx >> (b+1)) == (istar >> (b+1)) && !((idx >> b) & 1u)) c0++;
            }
            int tot = blockSum(c0);
            if (tot >= need) { } else { need -= tot; istar |= (1u << b); }
        }
        for (int j = tid & 3; j < cw; j += 4) {
            uint2 e = lw[j];
            if (e.x > T || (e.x == T && e.y <= istar)) {
                int slot = atomicAdd(&s_cnt2, 1);
                s_ff[slot] = e.x; s_fi[slot] = (int)e.y;
            }
        }
        if (tid < KPP) {
            unsigned idx = (unsigned)(NEXT_BASE + tid);
            if (nkk > T || (nkk == T && idx <= istar)) {
                int slot = atomicAdd(&s_cnt2, 1);
                s_ff[slot] = nkk; s_fi[slot] = (int)idx;
            }
        }
        __syncthreads();
        for (int e = tid; e < WID; e += 256) {
            unsigned mf = s_ff[e]; int mi = s_fi[e];
            int rank = 0;
            for (int j = 0; j < WID; ++j) {
                unsigned f = s_ff[j];
                rank += (f > mf || (f == mf && s_fi[j] < mi)) ? 1 : 0;
            }
            s_selidx[rank] = mi; s_selval[rank] = funkey(mf);
        }
    }
    __syncthreads();

    // epilogue: per-k scalar outputs
    if (tid < WID) {
        int k = tid;
        int ind = s_selidx[k];
        bool noext = ind >= NEXT_BASE;
        int src  = noext ? (ind - NEXT_BASE) : (ind >> 11);
        int extk = ind & (VV-1);
        int plen = ylens[n*KPP + src];
        int lens = plen + (noext ? 0 : 1);
        float nbv = noext ? s_nbne[src] : s_selval[k];
        float bv  = noext ? s_bne[src]  : 0.0f;
        int lastv = noext ? s_last[src] : extk;
        size_t o = (size_t)n*WID + k;
        out[O_LAST  + o] = (float)lastv;
        out[O_LENS  + o] = (float)lens;
        out[O_NB    + o] = nbv;
        out[O_B     + o] = bv;
        out[O_SRC   + o] = (float)src;
        out[O_NOEXT + o] = noext ? 1.0f : 0.0f;
        s_r_src[k] = src; s_r_lens[k] = lens; s_r_ext[k] = extk;
        s_r_noext[k] = noext ? 1 : 0;
    }
    __syncthreads();

    // fused next_is_prefix (all 1024 (k,j) pairs with 256 threads)
    for (int i = tid; i < WID*WID; i += 256) {
        int k = i >> 5, j = i & 31;
        int src_j = s_r_src[j];
        int no_k  = s_r_noext[k], no_j = s_r_noext[j];
        int lens_k = s_r_lens[k], lens_j = s_r_lens[j];
        int plen_j = lens_j - (no_j ? 0 : 1);
        bool prefix = pip[((size_t)n*KPP + s_r_src[k])*KPP + src_j] != 0;
        bool leq    = lens_k <= lens_j;
        int  tstar  = max(lens_k - 1, 0);
        int  tmj;
        if (tstar == plen_j)   tmj = s_r_ext[j];
        else if (tstar < SS)   tmj = yprev[((size_t)tstar*NB + n)*KPP + src_j];
        else                   tmj = 0;
        bool res = prefix && leq && (no_k || (tmj == s_r_ext[k]));
        out[O_PREF + (size_t)n*WID*WID + i] = res ? 1.0f : 0.0f;
    }

    // fused y_next: out[t][n][k]
    for (int id = tid; id < (SS+1)*WID; id += 256) {
        int t = id >> 5, kq = id & 31;
        int src  = s_r_src[kq];
        int plen = s_r_lens[kq] - (s_r_noext[kq] ? 0 : 1);
        float val;
        if (t == plen)   val = (float)s_r_ext[kq];
        else if (t < SS) val = (float)yprev[((size_t)t*NB + n)*KPP + src];
        else             val = 0.0f;
        out[(size_t)t*NK + (size_t)n*WID + kq] = val;
    }
}

extern "C" void kernel_launch(void* const* d_in, const int* in_sizes, int n_in,
                              void* d_out, int out_size, void* d_ws, size_t ws_size,
                              hipStream_t stream) {
    const float* ext    = (const float*)d_in[0];
    const float* nonext = (const float*)d_in[1];
    const float* blank  = (const float*)d_in[2];
    const float* nbp    = (const float*)d_in[3];
    const float* bp     = (const float*)d_in[4];
    const int*   yprev  = (const int*)d_in[5];
    const int*   ylast  = (const int*)d_in[6];
    const int*   ylens  = (const int*)d_in[7];
    const int*   pip    = (const int*)d_in[8];
    float* out = (float*)d_out;

    uint2*    wsS  = (uint2*)d_ws;                                   // 8 MB
    int*      wsC  = (int*)((char*)d_ws + (size_t)NB*NWAVE*CAPW*8);  // 32 KB
    unsigned* wsT  = (unsigned*)(wsC + NB*NWAVE);                    // 32 KB
    float*    wsAb = (float*)(wsT + NB*NWAVE);                       // 512 KB

    slice_topk_kernel<<<NB*KBLK, 256, 0, stream>>>(ext, nbp, bp, yprev, ylast,
                                                   ylens, pip, wsS, wsC, wsT, wsAb);
    merge_kernel<<<NB, 256, 0, stream>>>(nonext, blank, nbp, bp, yprev,
                                         ylast, ylens, pip, wsS, wsC, wsT, wsAb, out);
}